// Round 1
// baseline (384.304 us; speedup 1.0000x reference)
//
#include <hip/hip_runtime.h>

typedef __attribute__((ext_vector_type(8))) short short8;
typedef __attribute__((ext_vector_type(4))) float f32x4;

#define SEQ 2048
#define NB 2
#define HID 1024
#define NH 16
#define HD 64
#define MS (NB * SEQ)  // 4096 rows total

__device__ inline ushort f2bf(float f) {
  union { float f; unsigned u; } x; x.f = f;
  unsigned r = x.u + 0x7fffu + ((x.u >> 16) & 1u);
  return (ushort)(r >> 16);
}

// ---------------- cast f32 -> bf16 ----------------
__global__ void cast_f32_bf16(const float* __restrict__ in, ushort* __restrict__ out, int n4) {
  int i = blockIdx.x * blockDim.x + threadIdx.x;
  if (i >= n4) return;
  float4 v = reinterpret_cast<const float4*>(in)[i];
  ushort4 o;
  o.x = f2bf(v.x); o.y = f2bf(v.y); o.z = f2bf(v.z); o.w = f2bf(v.w);
  reinterpret_cast<ushort4*>(out)[i] = o;
}

// ---------------- GEMM: C[M,N] = A[M,K] * B[N,K]^T + bias ----------------
// A, B bf16 row-major (K contiguous). OUT_BF16: 1 -> bf16 out, 0 -> f32 out.
template <int OUT_BF16>
__global__ __launch_bounds__(256) void gemm_bt(const ushort* __restrict__ A,
                                               const ushort* __restrict__ B,
                                               const float* __restrict__ bias,
                                               void* __restrict__ Cv,
                                               int M, int N, int K) {
  __shared__ ushort As[128][40];
  __shared__ ushort Bs[128][40];
  const int tid = threadIdx.x;
  const int wave = tid >> 6, lane = tid & 63;
  const int lr = lane & 15, lg = lane >> 4;
  const int wr = wave >> 1, wc = wave & 1;  // 2x2 waves, 64x64 each
  const int bm = blockIdx.y, bn = blockIdx.x;

  f32x4 acc[4][4];
#pragma unroll
  for (int i = 0; i < 4; ++i)
#pragma unroll
    for (int j = 0; j < 4; ++j) acc[i][j] = (f32x4)(0.f);

  const int ldr = tid >> 1;
  const int ldc = (tid & 1) * 16;
  const size_t arow = (size_t)(bm * 128 + ldr) * K + ldc;
  const size_t brow = (size_t)(bn * 128 + ldr) * K + ldc;

  for (int k0 = 0; k0 < K; k0 += 32) {
    short8 a0 = *reinterpret_cast<const short8*>(&A[arow + k0]);
    short8 a1 = *reinterpret_cast<const short8*>(&A[arow + k0 + 8]);
    short8 b0 = *reinterpret_cast<const short8*>(&B[brow + k0]);
    short8 b1 = *reinterpret_cast<const short8*>(&B[brow + k0 + 8]);
    *reinterpret_cast<short8*>(&As[ldr][ldc]) = a0;
    *reinterpret_cast<short8*>(&As[ldr][ldc + 8]) = a1;
    *reinterpret_cast<short8*>(&Bs[ldr][ldc]) = b0;
    *reinterpret_cast<short8*>(&Bs[ldr][ldc + 8]) = b1;
    __syncthreads();
    short8 af[4], bf[4];
#pragma unroll
    for (int i = 0; i < 4; ++i)
      af[i] = *reinterpret_cast<const short8*>(&As[wr * 64 + i * 16 + lr][lg * 8]);
#pragma unroll
    for (int i = 0; i < 4; ++i)
      bf[i] = *reinterpret_cast<const short8*>(&Bs[wc * 64 + i * 16 + lr][lg * 8]);
#pragma unroll
    for (int i = 0; i < 4; ++i)
#pragma unroll
      for (int j = 0; j < 4; ++j)
        acc[i][j] = __builtin_amdgcn_mfma_f32_16x16x32_bf16(af[i], bf[j], acc[i][j], 0, 0, 0);
    __syncthreads();
  }

#pragma unroll
  for (int i = 0; i < 4; ++i)
#pragma unroll
    for (int j = 0; j < 4; ++j) {
      const int row = bm * 128 + wr * 64 + i * 16 + lg * 4;
      const int col = bn * 128 + wc * 64 + j * 16 + lr;
      const float bv = bias ? bias[col] : 0.f;
#pragma unroll
      for (int r = 0; r < 4; ++r) {
        float v = acc[i][j][r] + bv;
        if (OUT_BF16)
          ((ushort*)Cv)[(size_t)(row + r) * N + col] = f2bf(v);
        else
          ((float*)Cv)[(size_t)(row + r) * N + col] = v;
      }
    }
}

// ---------------- flash attention ----------------
// Q,K,V,O: bf16 [B*S, HID] row-major; head h uses cols h*64..h*64+63.
// grid: (B*NH, SEQ/128), block 256. Each wave: 32 q-rows. KV tile = 64 keys.
__global__ __launch_bounds__(256) void attn_kernel(const ushort* __restrict__ Q,
                                                   const ushort* __restrict__ Kp,
                                                   const ushort* __restrict__ Vp,
                                                   ushort* __restrict__ Op) {
  __shared__ ushort Ks[64][72];
  __shared__ ushort Vt[64][72];
  __shared__ ushort Ps[4][32][72];

  const int b = blockIdx.x >> 4;
  const int h = blockIdx.x & 15;
  const int qt = blockIdx.y;
  const int tid = threadIdx.x;
  const int wave = tid >> 6;
  const int lane = tid & 63;
  const int lr = lane & 15;
  const int lg = lane >> 4;

  const size_t base = (size_t)b * SEQ * HID + h * HD;

  // Q fragments held in registers for the whole block of 32 KV tiles
  short8 qf[2][2];
#pragma unroll
  for (int m = 0; m < 2; ++m)
#pragma unroll
    for (int kk = 0; kk < 2; ++kk) {
      int row = qt * 128 + wave * 32 + m * 16 + lr;
      qf[m][kk] =
          *reinterpret_cast<const short8*>(&Q[base + (size_t)row * HID + kk * 32 + lg * 8]);
    }

  f32x4 acc[2][4];
  float mrun[2][4], lrun[2][4];
#pragma unroll
  for (int m = 0; m < 2; ++m)
#pragma unroll
    for (int n = 0; n < 4; ++n) acc[m][n] = (f32x4)(0.f);
#pragma unroll
  for (int m = 0; m < 2; ++m)
#pragma unroll
    for (int r = 0; r < 4; ++r) { mrun[m][r] = -1e30f; lrun[m][r] = 0.f; }

  const int key0 = tid >> 2;        // 0..63
  const int c0 = (tid & 3) * 16;    // dim chunk

  for (int kt = 0; kt < SEQ / 64; ++kt) {
    // ---- stage K tile (row-major) and V tile (transposed) ----
    {
      size_t g = base + (size_t)(kt * 64 + key0) * HID + c0;
      short8 k0v = *reinterpret_cast<const short8*>(&Kp[g]);
      short8 k1v = *reinterpret_cast<const short8*>(&Kp[g + 8]);
      *reinterpret_cast<short8*>(&Ks[key0][c0]) = k0v;
      *reinterpret_cast<short8*>(&Ks[key0][c0 + 8]) = k1v;
      short8 v0 = *reinterpret_cast<const short8*>(&Vp[g]);
      short8 v1 = *reinterpret_cast<const short8*>(&Vp[g + 8]);
      ushort tmp[16];
      *reinterpret_cast<short8*>(&tmp[0]) = v0;
      *reinterpret_cast<short8*>(&tmp[8]) = v1;
#pragma unroll
      for (int j = 0; j < 16; ++j) Vt[c0 + j][key0] = tmp[j];
    }
    __syncthreads();

    // ---- S = Q K^T (per wave: 32 rows x 64 keys) ----
    f32x4 sa[2][4];
#pragma unroll
    for (int m = 0; m < 2; ++m)
#pragma unroll
      for (int n = 0; n < 4; ++n) sa[m][n] = (f32x4)(0.f);
#pragma unroll
    for (int kk = 0; kk < 2; ++kk) {
      short8 kf[4];
#pragma unroll
      for (int n = 0; n < 4; ++n)
        kf[n] = *reinterpret_cast<const short8*>(&Ks[n * 16 + lr][kk * 32 + lg * 8]);
#pragma unroll
      for (int m = 0; m < 2; ++m)
#pragma unroll
        for (int n = 0; n < 4; ++n)
          sa[m][n] = __builtin_amdgcn_mfma_f32_16x16x32_bf16(qf[m][kk], kf[n], sa[m][n], 0, 0, 0);
    }

    // ---- online softmax (rows: m*16 + lg*4 + r; cols: n*16 + lr) ----
#pragma unroll
    for (int m = 0; m < 2; ++m)
#pragma unroll
      for (int r = 0; r < 4; ++r) {
        float sv[4];
        float smax = -1e30f;
#pragma unroll
        for (int n = 0; n < 4; ++n) {
          sv[n] = sa[m][n][r] * 0.125f;
          smax = fmaxf(smax, sv[n]);
        }
#pragma unroll
        for (int off = 1; off < 16; off <<= 1) smax = fmaxf(smax, __shfl_xor(smax, off, 64));
        float mnew = fmaxf(mrun[m][r], smax);
        float corr = __expf(mrun[m][r] - mnew);
        mrun[m][r] = mnew;
        float psum = 0.f;
#pragma unroll
        for (int n = 0; n < 4; ++n) {
          float p = __expf(sv[n] - mnew);
          psum += p;
          Ps[wave][m * 16 + lg * 4 + r][n * 16 + lr] = f2bf(p);
        }
#pragma unroll
        for (int off = 1; off < 16; off <<= 1) psum += __shfl_xor(psum, off, 64);
        lrun[m][r] = lrun[m][r] * corr + psum;
#pragma unroll
        for (int n = 0; n < 4; ++n) acc[m][n][r] *= corr;
      }

    // ---- O += P V ----
#pragma unroll
    for (int kk = 0; kk < 2; ++kk) {
      short8 vf[4], pf[2];
#pragma unroll
      for (int n = 0; n < 4; ++n)
        vf[n] = *reinterpret_cast<const short8*>(&Vt[n * 16 + lr][kk * 32 + lg * 8]);
#pragma unroll
      for (int m = 0; m < 2; ++m)
        pf[m] = *reinterpret_cast<const short8*>(&Ps[wave][m * 16 + lr][kk * 32 + lg * 8]);
#pragma unroll
      for (int m = 0; m < 2; ++m)
#pragma unroll
        for (int n = 0; n < 4; ++n)
          acc[m][n] = __builtin_amdgcn_mfma_f32_16x16x32_bf16(pf[m], vf[n], acc[m][n], 0, 0, 0);
    }
    __syncthreads();
  }

  // ---- normalize and write ----
#pragma unroll
  for (int m = 0; m < 2; ++m)
#pragma unroll
    for (int r = 0; r < 4; ++r) {
      float linv = 1.f / lrun[m][r];
      int row = qt * 128 + wave * 32 + m * 16 + lg * 4 + r;
#pragma unroll
      for (int n = 0; n < 4; ++n)
        Op[base + (size_t)row * HID + n * 16 + lr] = f2bf(acc[m][n][r] * linv);
    }
}

// ---------------- launch ----------------
extern "C" void kernel_launch(void* const* d_in, const int* in_sizes, int n_in,
                              void* d_out, int out_size, void* d_ws, size_t ws_size,
                              hipStream_t stream) {
  const float* query = (const float*)d_in[0];
  const float* key   = (const float*)d_in[1];
  const float* value = (const float*)d_in[2];
  const float* Wq = (const float*)d_in[3];
  const float* bq = (const float*)d_in[4];
  const float* Wk = (const float*)d_in[5];
  const float* bk = (const float*)d_in[6];
  const float* Wv = (const float*)d_in[7];
  const float* bv = (const float*)d_in[8];
  const float* Wo = (const float*)d_in[9];
  const float* bo = (const float*)d_in[10];

  const size_t actElems = (size_t)MS * HID;       // 4194304
  const size_t wElems = (size_t)HID * HID;        // 1048576
  char* ws = (char*)d_ws;
  ushort* qb = (ushort*)(ws + 0);                 // 8MB each
  ushort* kb = (ushort*)(ws + actElems * 2);
  ushort* vb = (ushort*)(ws + actElems * 4);
  ushort* wq = (ushort*)(ws + actElems * 6);      // 2MB each
  ushort* wk = (ushort*)(ws + actElems * 6 + wElems * 2);
  ushort* wv = (ushort*)(ws + actElems * 6 + wElems * 4);
  ushort* wo = (ushort*)(ws + actElems * 6 + wElems * 6);
  ushort* Qp   = (ushort*)(ws + actElems * 6 + wElems * 8);
  ushort* Kp   = (ushort*)(ws + actElems * 8 + wElems * 8);
  ushort* Vp   = (ushort*)(ws + actElems * 10 + wElems * 8);
  ushort* attn = (ushort*)(ws + actElems * 12 + wElems * 8);

  const int actB = (int)(actElems / 4 / 256);  // 4096 blocks
  const int wB = (int)(wElems / 4 / 256);      // 1024 blocks
  cast_f32_bf16<<<actB, 256, 0, stream>>>(query, qb, (int)(actElems / 4));
  cast_f32_bf16<<<actB, 256, 0, stream>>>(key, kb, (int)(actElems / 4));
  cast_f32_bf16<<<actB, 256, 0, stream>>>(value, vb, (int)(actElems / 4));
  cast_f32_bf16<<<wB, 256, 0, stream>>>(Wq, wq, (int)(wElems / 4));
  cast_f32_bf16<<<wB, 256, 0, stream>>>(Wk, wk, (int)(wElems / 4));
  cast_f32_bf16<<<wB, 256, 0, stream>>>(Wv, wv, (int)(wElems / 4));
  cast_f32_bf16<<<wB, 256, 0, stream>>>(Wo, wo, (int)(wElems / 4));

  dim3 gg(HID / 128, MS / 128);  // (8, 32)
  gemm_bt<1><<<gg, 256, 0, stream>>>(qb, wq, bq, Qp, MS, HID, HID);
  gemm_bt<1><<<gg, 256, 0, stream>>>(kb, wk, bk, Kp, MS, HID, HID);
  gemm_bt<1><<<gg, 256, 0, stream>>>(vb, wv, bv, Vp, MS, HID, HID);

  dim3 ga(NB * NH, SEQ / 128);  // (32, 16)
  attn_kernel<<<ga, 256, 0, stream>>>(Qp, Kp, Vp, attn);

  gemm_bt<0><<<gg, 256, 0, stream>>>(attn, wo, bo, (float*)d_out, MS, HID, HID);
}

// Round 2
// 284.352 us; speedup vs baseline: 1.3515x; 1.3515x over previous
//
#include <hip/hip_runtime.h>

typedef __attribute__((ext_vector_type(8))) short short8;
typedef __attribute__((ext_vector_type(4))) float f32x4;

#define SEQ 2048
#define NB 2
#define HID 1024
#define NH 16
#define HD 64
#define MS (NB * SEQ)  // 4096 rows total

typedef const __attribute__((address_space(1))) unsigned int* gptr_t;
typedef __attribute__((address_space(3))) unsigned int* lptr_t;

__device__ inline ushort f2bf(float f) {
  union { float f; unsigned u; } x; x.f = f;
  unsigned r = x.u + 0x7fffu + ((x.u >> 16) & 1u);
  return (ushort)(r >> 16);
}

// ---------------- casts ----------------
__global__ void cast3(const float* __restrict__ a, const float* __restrict__ b,
                      const float* __restrict__ c, ushort* __restrict__ oa,
                      ushort* __restrict__ ob, ushort* __restrict__ oc, int n4) {
  const int z = blockIdx.y;
  const float* in = (z == 0) ? a : (z == 1) ? b : c;
  ushort* out = (z == 0) ? oa : (z == 1) ? ob : oc;
  int i = blockIdx.x * 256 + threadIdx.x;
  if (i >= n4) return;
  float4 v = reinterpret_cast<const float4*>(in)[i];
  ushort4 o;
  o.x = f2bf(v.x); o.y = f2bf(v.y); o.z = f2bf(v.z); o.w = f2bf(v.w);
  reinterpret_cast<ushort4*>(out)[i] = o;
}

__global__ void cast4(const float* __restrict__ a, const float* __restrict__ b,
                      const float* __restrict__ c, const float* __restrict__ d,
                      ushort* __restrict__ oa, ushort* __restrict__ ob,
                      ushort* __restrict__ oc, ushort* __restrict__ od, int n4) {
  const int z = blockIdx.y;
  const float* in = (z == 0) ? a : (z == 1) ? b : (z == 2) ? c : d;
  ushort* out = (z == 0) ? oa : (z == 1) ? ob : (z == 2) ? oc : od;
  int i = blockIdx.x * 256 + threadIdx.x;
  if (i >= n4) return;
  float4 v = reinterpret_cast<const float4*>(in)[i];
  ushort4 o;
  o.x = f2bf(v.x); o.y = f2bf(v.y); o.z = f2bf(v.z); o.w = f2bf(v.w);
  reinterpret_cast<ushort4*>(out)[i] = o;
}

// ---------------- GEMM body: C[M,N] = A[M,K] * B[N,K]^T + bias ----------------
// m97-style: global_load_lds(16B) staging, linear LDS [128][32], 128x128 tile.
template <int OUT_BF16>
__device__ __forceinline__ void gemm_body(const ushort* __restrict__ A,
                                          const ushort* __restrict__ B,
                                          const float* __restrict__ bias,
                                          ushort* __restrict__ Obf,
                                          float* __restrict__ Of) {
  __shared__ alignas(16) ushort As[128 * 32];
  __shared__ alignas(16) ushort Bs[128 * 32];
  const int tid = threadIdx.x;
  const int wave = tid >> 6, lane = tid & 63;
  const int lr = lane & 15, lg = lane >> 4;
  const int wr = wave >> 1, wc = wave & 1;  // 2x2 waves, 64x64 each
  const int bm = blockIdx.y, bn = blockIdx.x;

  f32x4 acc[4][4];
#pragma unroll
  for (int i = 0; i < 4; ++i)
#pragma unroll
    for (int j = 0; j < 4; ++j) acc[i][j] = (f32x4)(0.f);

  const int l4 = lane >> 2;          // 0..15 row within chunk
  const int lc = (lane & 3) * 8;     // col elements

  for (int k0 = 0; k0 < HID; k0 += 32) {
#pragma unroll
    for (int c = 0; c < 2; ++c) {
      const int chunk = wave * 2 + c;
      const ushort* ga = &A[(size_t)(bm * 128 + chunk * 16 + l4) * HID + k0 + lc];
      const ushort* gb = &B[(size_t)(bn * 128 + chunk * 16 + l4) * HID + k0 + lc];
      __builtin_amdgcn_global_load_lds((gptr_t)(const void*)ga, (lptr_t)(void*)&As[chunk * 512], 16, 0, 0);
      __builtin_amdgcn_global_load_lds((gptr_t)(const void*)gb, (lptr_t)(void*)&Bs[chunk * 512], 16, 0, 0);
    }
    __syncthreads();
    short8 af[4], bf[4];
#pragma unroll
    for (int i = 0; i < 4; ++i)
      af[i] = *reinterpret_cast<const short8*>(&As[(wr * 64 + i * 16 + lr) * 32 + lg * 8]);
#pragma unroll
    for (int j = 0; j < 4; ++j)
      bf[j] = *reinterpret_cast<const short8*>(&Bs[(wc * 64 + j * 16 + lr) * 32 + lg * 8]);
#pragma unroll
    for (int i = 0; i < 4; ++i)
#pragma unroll
      for (int j = 0; j < 4; ++j)
        acc[i][j] = __builtin_amdgcn_mfma_f32_16x16x32_bf16(af[i], bf[j], acc[i][j], 0, 0, 0);
    __syncthreads();
  }

#pragma unroll
  for (int i = 0; i < 4; ++i)
#pragma unroll
    for (int j = 0; j < 4; ++j) {
      const int row = bm * 128 + wr * 64 + i * 16 + lg * 4;
      const int col = bn * 128 + wc * 64 + j * 16 + lr;
      const float bv = bias[col];
#pragma unroll
      for (int r = 0; r < 4; ++r) {
        float v = acc[i][j][r] + bv;
        if (OUT_BF16)
          Obf[(size_t)(row + r) * HID + col] = f2bf(v);
        else
          Of[(size_t)(row + r) * HID + col] = v;
      }
    }
}

__global__ __launch_bounds__(256) void gemm_qkv(const ushort* __restrict__ A0, const ushort* __restrict__ A1,
                                                const ushort* __restrict__ A2, const ushort* __restrict__ W0,
                                                const ushort* __restrict__ W1, const ushort* __restrict__ W2,
                                                const float* __restrict__ b0, const float* __restrict__ b1,
                                                const float* __restrict__ b2, ushort* __restrict__ O0,
                                                ushort* __restrict__ O1, ushort* __restrict__ O2) {
  const int z = blockIdx.z;
  const ushort* A = (z == 0) ? A0 : (z == 1) ? A1 : A2;
  const ushort* W = (z == 0) ? W0 : (z == 1) ? W1 : W2;
  const float* bias = (z == 0) ? b0 : (z == 1) ? b1 : b2;
  ushort* O = (z == 0) ? O0 : (z == 1) ? O1 : O2;
  gemm_body<1>(A, W, bias, O, nullptr);
}

__global__ __launch_bounds__(256) void gemm_wo(const ushort* __restrict__ A, const ushort* __restrict__ W,
                                               const float* __restrict__ bias, float* __restrict__ O) {
  gemm_body<0>(A, W, bias, nullptr, O);
}

// ---------------- flash attention (swapped QK^T, in-register softmax) ----------------
// grid (NB*NH, SEQ/64), 256 threads = 4 waves, each wave owns 16 q-rows.
__global__ __launch_bounds__(256) void attn_kernel(const ushort* __restrict__ Q,
                                                   const ushort* __restrict__ Kp,
                                                   const ushort* __restrict__ Vp,
                                                   ushort* __restrict__ Op) {
  __shared__ alignas(16) ushort Ks[64 * 64];  // linear; content pre-swizzled for XOR-read
  __shared__ alignas(16) ushort Vt[64][72];   // V transposed [d][key]

  const int b = blockIdx.x >> 4;
  const int h = blockIdx.x & 15;
  const int qt = blockIdx.y;
  const int tid = threadIdx.x;
  const int wave = tid >> 6;
  const int lane = tid & 63;
  const int lr = lane & 15;
  const int lg = lane >> 4;

  const size_t base = (size_t)b * SEQ * HID + h * HD;

  // Q fragments (B-operand: rows = q), held for all KV tiles
  short8 qf[2];
  const int qrow = qt * 64 + wave * 16 + lr;
#pragma unroll
  for (int kk = 0; kk < 2; ++kk)
    qf[kk] = *reinterpret_cast<const short8*>(&Q[base + (size_t)qrow * HID + kk * 32 + lg * 8]);

  f32x4 acc[4];  // O^T: acc[nd][r] = O[q=lr][d = nd*16 + lg*4 + r]
#pragma unroll
  for (int nd = 0; nd < 4; ++nd) acc[nd] = (f32x4)(0.f);
  float mrun = -1e30f, lrun = 0.f;

  // staging assignments
  const int key0 = tid >> 2;           // V staging: key row 0..63
  const int c0 = (tid & 3) * 16;       // V staging: dim chunk
  const int krow_sub = lane >> 3;      // K staging: row within chunk
  const int kcol = ((lane & 7) ^ (lane >> 3)) * 8;  // inverse-swizzled source col
  // P redistribution source lanes
  const int s0 = lr + ((lg & 1) << 5);
  const int s1v = s0 + 16;

  for (int kt = 0; kt < SEQ / 64; ++kt) {
    // ---- stage K via global_load_lds (pre-swizzled source) ----
#pragma unroll
    for (int c = 0; c < 2; ++c) {
      const int chunk = wave * 2 + c;
      const int krow = chunk * 8 + krow_sub;
      const ushort* gk = &Kp[base + (size_t)(kt * 64 + krow) * HID + kcol];
      __builtin_amdgcn_global_load_lds((gptr_t)(const void*)gk, (lptr_t)(void*)&Ks[chunk * 512], 16, 0, 0);
    }
    // ---- stage V transposed (manual) ----
    {
      const size_t g = base + (size_t)(kt * 64 + key0) * HID + c0;
      short8 v0 = *reinterpret_cast<const short8*>(&Vp[g]);
      short8 v1 = *reinterpret_cast<const short8*>(&Vp[g + 8]);
      ushort tmp[16];
      *reinterpret_cast<short8*>(&tmp[0]) = v0;
      *reinterpret_cast<short8*>(&tmp[8]) = v1;
#pragma unroll
      for (int j = 0; j < 16; ++j) Vt[c0 + j][key0] = tmp[j];
    }
    __syncthreads();

    // ---- S^T = K Q^T: sa[n][r] = S[k = n*16 + lg*4 + r][q = lr] ----
    f32x4 sa[4];
#pragma unroll
    for (int n = 0; n < 4; ++n) sa[n] = (f32x4)(0.f);
#pragma unroll
    for (int kk = 0; kk < 2; ++kk) {
      short8 kf[4];
#pragma unroll
      for (int n = 0; n < 4; ++n) {
        const int row = n * 16 + lr;
        const int cb = (kk * 64 + lg * 16) ^ ((lr & 7) << 4);
        kf[n] = *reinterpret_cast<const short8*>((const char*)Ks + row * 128 + cb);
      }
#pragma unroll
      for (int n = 0; n < 4; ++n)
        sa[n] = __builtin_amdgcn_mfma_f32_16x16x32_bf16(kf[n], qf[kk], sa[n], 0, 0, 0);
    }

    // ---- online softmax, fully in-register ----
    float pmax = -1e30f;
#pragma unroll
    for (int n = 0; n < 4; ++n)
#pragma unroll
      for (int r = 0; r < 4; ++r) {
        float s = sa[n][r] * 0.125f;
        sa[n][r] = s;
        pmax = fmaxf(pmax, s);
      }
    pmax = fmaxf(pmax, __shfl_xor(pmax, 16, 64));
    pmax = fmaxf(pmax, __shfl_xor(pmax, 32, 64));
    if (__any(pmax > mrun + 8.f)) {  // defer-max: rescale only when needed
      const float mnew = fmaxf(mrun, pmax);
      const float corr = __expf(mrun - mnew);
      mrun = mnew;
      lrun *= corr;
#pragma unroll
      for (int nd = 0; nd < 4; ++nd) acc[nd] *= corr;
    }
    float psum = 0.f;
#pragma unroll
    for (int n = 0; n < 4; ++n)
#pragma unroll
      for (int r = 0; r < 4; ++r) {
        float p = __expf(sa[n][r] - mrun);
        sa[n][r] = p;
        psum += p;
      }
    psum += __shfl_xor(psum, 16, 64);
    psum += __shfl_xor(psum, 32, 64);
    lrun += psum;

    // ---- V^T fragments (A-operand: rows = d) ----
    short8 vtf[4][2];
#pragma unroll
    for (int nd = 0; nd < 4; ++nd)
#pragma unroll
      for (int kk = 0; kk < 2; ++kk)
        vtf[nd][kk] = *reinterpret_cast<const short8*>(&Vt[nd * 16 + lr][kk * 32 + lg * 8]);

    // ---- P redistribution + O^T += V^T P^T ----
#pragma unroll
    for (int kk = 0; kk < 2; ++kk) {
      unsigned pw0 = 0, pw1 = 0, pw2 = 0, pw3 = 0;
#pragma unroll
      for (int half = 0; half < 2; ++half) {
        const int nsel = kk * 2 + half;
        unsigned w0 = ((unsigned)f2bf(sa[nsel][1]) << 16) | f2bf(sa[nsel][0]);
        unsigned w1 = ((unsigned)f2bf(sa[nsel][3]) << 16) | f2bf(sa[nsel][2]);
        int d0 = __shfl((int)w0, s0, 64);
        int d1 = __shfl((int)w1, s0, 64);
        int d2 = __shfl((int)w0, s1v, 64);
        int d3 = __shfl((int)w1, s1v, 64);
        const bool take = ((lg >> 1) == half);
        pw0 = take ? (unsigned)d0 : pw0;
        pw1 = take ? (unsigned)d1 : pw1;
        pw2 = take ? (unsigned)d2 : pw2;
        pw3 = take ? (unsigned)d3 : pw3;
      }
      union { unsigned u[4]; short8 v; } pu;
      pu.u[0] = pw0; pu.u[1] = pw1; pu.u[2] = pw2; pu.u[3] = pw3;
#pragma unroll
      for (int nd = 0; nd < 4; ++nd)
        acc[nd] = __builtin_amdgcn_mfma_f32_16x16x32_bf16(vtf[nd][kk], pu.v, acc[nd], 0, 0, 0);
    }
    __syncthreads();
  }

  // ---- normalize and write (per-lane: col q = lr matches softmax state) ----
  const float linv = 1.f / lrun;
#pragma unroll
  for (int nd = 0; nd < 4; ++nd) {
    ushort4 o;
    o.x = f2bf(acc[nd][0] * linv);
    o.y = f2bf(acc[nd][1] * linv);
    o.z = f2bf(acc[nd][2] * linv);
    o.w = f2bf(acc[nd][3] * linv);
    *reinterpret_cast<ushort4*>(&Op[base + (size_t)qrow * HID + nd * 16 + lg * 4]) = o;
  }
}

// ---------------- launch ----------------
extern "C" void kernel_launch(void* const* d_in, const int* in_sizes, int n_in,
                              void* d_out, int out_size, void* d_ws, size_t ws_size,
                              hipStream_t stream) {
  const float* query = (const float*)d_in[0];
  const float* key   = (const float*)d_in[1];
  const float* value = (const float*)d_in[2];
  const float* Wq = (const float*)d_in[3];
  const float* bq = (const float*)d_in[4];
  const float* Wk = (const float*)d_in[5];
  const float* bk = (const float*)d_in[6];
  const float* Wv = (const float*)d_in[7];
  const float* bv = (const float*)d_in[8];
  const float* Wo = (const float*)d_in[9];
  const float* bo = (const float*)d_in[10];

  const size_t actElems = (size_t)MS * HID;  // 4194304
  const size_t wElems = (size_t)HID * HID;   // 1048576
  char* ws = (char*)d_ws;
  ushort* qb = (ushort*)(ws + 0);
  ushort* kb = (ushort*)(ws + actElems * 2);
  ushort* vb = (ushort*)(ws + actElems * 4);
  ushort* wq = (ushort*)(ws + actElems * 6);
  ushort* wk = (ushort*)(ws + actElems * 6 + wElems * 2);
  ushort* wv = (ushort*)(ws + actElems * 6 + wElems * 4);
  ushort* wo = (ushort*)(ws + actElems * 6 + wElems * 6);
  ushort* Qp   = (ushort*)(ws + actElems * 6 + wElems * 8);
  ushort* Kp   = (ushort*)(ws + actElems * 8 + wElems * 8);
  ushort* Vp   = (ushort*)(ws + actElems * 10 + wElems * 8);
  ushort* attn = (ushort*)(ws + actElems * 12 + wElems * 8);

  dim3 cg3((unsigned)(actElems / 4 / 256), 3);
  cast3<<<cg3, 256, 0, stream>>>(query, key, value, qb, kb, vb, (int)(actElems / 4));
  dim3 cg4((unsigned)(wElems / 4 / 256), 4);
  cast4<<<cg4, 256, 0, stream>>>(Wq, Wk, Wv, Wo, wq, wk, wv, wo, (int)(wElems / 4));

  dim3 gq(HID / 128, MS / 128, 3);  // (8, 32, 3) = 768 blocks, 3 blocks/CU
  gemm_qkv<<<gq, 256, 0, stream>>>(qb, kb, vb, wq, wk, wv, bq, bk, bv, Qp, Kp, Vp);

  dim3 ga(NB * NH, SEQ / 64);  // (32, 32) = 1024 blocks, 4 blocks/CU
  attn_kernel<<<ga, 256, 0, stream>>>(Qp, Kp, Vp, attn);

  dim3 go(HID / 128, MS / 128);  // (8, 32)
  gemm_wo<<<go, 256, 0, stream>>>(attn, wo, bo, (float*)d_out);
}